// Round 1
// baseline (196.718 us; speedup 1.0000x reference)
//
#include <hip/hip_runtime.h>
#include <stdint.h>

// CRF mean-NLL, B=1024 S=1024 T=16.
// logZ via exp-domain linear recurrence: u_t = N_t u_{t-1}, N_t = diag(exp(em_t)) * exp(trans)^T.
// Phase 1: chunk the 1023 steps into 16 chunks of 64; each wave builds P_c = prod N_t via
//          bf16 MFMA 16x16x16 (D layout == next B-operand layout, zero shuffle cost),
//          with power-of-2 rescaling every 8 steps (exponent tracked exactly).
// Phase 2: per batch, 16 sequential 16x16 matvecs in fp32 + log-domain scale accumulation.
// Gold score: trivial gather-sum. Final: mean(logZ - gold) -> d_out[0] (fp32).

#define BB 1024
#define SS 1024
#define TT 16
#define CC 16   // chunks per batch
#define LL 64   // steps per chunk

typedef float  f32x4 __attribute__((ext_vector_type(4)));
typedef short  s16x4 __attribute__((ext_vector_type(4)));
typedef uint32_t u32x2 __attribute__((ext_vector_type(2)));

__device__ __forceinline__ uint32_t pack_bf16(float lo, float hi) {
    // round-half-up bf16 pack (bias ~2^-25, negligible; inputs are positive normals)
    uint32_t a = __float_as_uint(lo) + 0x8000u;
    uint32_t b = __float_as_uint(hi) + 0x8000u;
    return (a >> 16) | (b & 0xFFFF0000u);
}

__device__ __forceinline__ s16x4 mk_frag(uint32_t lo, uint32_t hi) {
    u32x2 t;
    t.x = lo; t.y = hi;
    return __builtin_bit_cast(s16x4, t);
}

// ---------------- Phase 1: chunk matrix products ----------------
__global__ __launch_bounds__(256, 4) void phase1_kernel(
        const float* __restrict__ em,      // (B,S,T)
        const float* __restrict__ trans,   // (T,T)
        float* __restrict__ mats,          // (B*C, 256)
        int*   __restrict__ scales)        // (B*C)
{
    const int wave = threadIdx.x >> 6;
    const int lane = threadIdx.x & 63;
    const int id   = blockIdx.x * 4 + wave;   // 0 .. B*C-1
    const int b    = id >> 4;
    const int c    = id & 15;
    const int q    = lane >> 4;               // quad: holds k = 4q+j (A) / rows 4q+r (D)
    const int m    = lane & 15;

    // A-operand constants: N_t[m][4q+j] = exp(trans[4q+j][m]) * x_t[m]
    const float e0 = __expf(trans[(4*q + 0) * TT + m]);
    const float e1 = __expf(trans[(4*q + 1) * TT + m]);
    const float e2 = __expf(trans[(4*q + 2) * TT + m]);
    const float e3 = __expf(trans[(4*q + 3) * TT + m]);

    // B operand starts as identity (bf16 1.0 = 0x3F80): B[k=4q+j][n=m]
    uint32_t bp0 = ((4*q + 0) == m ? 0x3F80u : 0u) | ((4*q + 1) == m ? (0x3F80u << 16) : 0u);
    uint32_t bp1 = ((4*q + 2) == m ? 0x3F80u : 0u) | ((4*q + 3) == m ? (0x3F80u << 16) : 0u);

    const int t0 = (c == 0) ? 1 : c * LL;     // forward steps are t = 1 .. S-1
    const int t1 = c * LL + LL;               // exclusive
    const float* ep = em + (size_t)b * SS * TT + m;

    int sc = 0;
    f32x4 d;
    const f32x4 zero = {0.f, 0.f, 0.f, 0.f};

    for (int t = t0; t < t1; ++t) {
        const float x = __expf(ep[t * TT]);   // 64B/wave, L1-broadcast
        const s16x4 af = mk_frag(pack_bf16(x * e0, x * e1), pack_bf16(x * e2, x * e3));
        const s16x4 bf = mk_frag(bp0, bp1);
        d = __builtin_amdgcn_mfma_f32_16x16x16bf16_1k(af, bf, zero, 0, 0, 0);

        if ((t & 7) == 7 || t == t1 - 1) {
            // power-of-2 rescale: keep max entry in [1,2), accumulate exponent exactly
            float mx = fmaxf(fmaxf(d[0], d[1]), fmaxf(d[2], d[3]));
            #pragma unroll
            for (int s = 1; s < 64; s <<= 1) mx = fmaxf(mx, __shfl_xor(mx, s, 64));
            const int e = (int)(__float_as_uint(mx) >> 23) - 127;
            const float sf = __uint_as_float((uint32_t)(127 - e) << 23);  // 2^-e
            d[0] *= sf; d[1] *= sf; d[2] *= sf; d[3] *= sf;
            sc += e;
        }
        bp0 = pack_bf16(d[0], d[1]);
        bp1 = pack_bf16(d[2], d[3]);
    }

    // store P_c (fp32): D reg r -> P[4q+r][m]; 1KB contiguous per wave
    float* mp = mats + (size_t)id * 256;
    mp[(4*q + 0) * TT + m] = d[0];
    mp[(4*q + 1) * TT + m] = d[1];
    mp[(4*q + 2) * TT + m] = d[2];
    mp[(4*q + 3) * TT + m] = d[3];
    if (lane == 0) scales[id] = sc;
}

// ---------------- Phase 2: sequential chunk combine ----------------
__global__ __launch_bounds__(256, 4) void phase2_kernel(
        const float* __restrict__ em,
        const float* __restrict__ startt,
        const float* __restrict__ endt,
        const float* __restrict__ mats,
        const int*   __restrict__ scales,
        float* __restrict__ logZ)
{
    const int wave = threadIdx.x >> 6;
    const int lane = threadIdx.x & 63;
    const int g    = lane >> 4;               // 4 batches per wave
    const int m    = lane & 15;
    const int b    = blockIdx.x * 16 + wave * 4 + g;
    const int base = lane & 48;

    // u0 = exp(start + em[:,0] - max)
    const float s0 = startt[m] + em[(size_t)b * SS * TT + m];
    float mx = s0;
    #pragma unroll
    for (int s = 1; s < 16; s <<= 1) mx = fmaxf(mx, __shfl_xor(mx, s, 16));
    float u   = __expf(s0 - mx);
    float ell = mx;

    for (int c = 0; c < CC; ++c) {
        const float* row = mats + (size_t)(b * CC + c) * 256 + m * TT;
        const f32x4 r0 = *(const f32x4*)(row + 0);
        const f32x4 r1 = *(const f32x4*)(row + 4);
        const f32x4 r2 = *(const f32x4*)(row + 8);
        const f32x4 r3 = *(const f32x4*)(row + 12);
        float acc = 0.f;
        #pragma unroll
        for (int k = 0; k < 4; ++k) acc += r0[k] * __shfl(u, base + k,      64);
        #pragma unroll
        for (int k = 0; k < 4; ++k) acc += r1[k] * __shfl(u, base + 4 + k,  64);
        #pragma unroll
        for (int k = 0; k < 4; ++k) acc += r2[k] * __shfl(u, base + 8 + k,  64);
        #pragma unroll
        for (int k = 0; k < 4; ++k) acc += r3[k] * __shfl(u, base + 12 + k, 64);

        float m2 = acc;
        #pragma unroll
        for (int s = 1; s < 16; s <<= 1) m2 = fmaxf(m2, __shfl_xor(m2, s, 16));
        u = acc / m2;
        ell += __logf(m2) + (float)scales[b * CC + c] * 0.6931471805599453f;
    }

    float v = u * __expf(endt[m]);
    #pragma unroll
    for (int s = 1; s < 16; s <<= 1) v += __shfl_xor(v, s, 16);
    if (m == 0) logZ[b] = ell + __logf(v);
}

// ---------------- Gold score ----------------
__global__ __launch_bounds__(256) void gold_kernel(
        const float* __restrict__ em,
        const int*   __restrict__ tags,    // int32 (JAX x64 disabled)
        const float* __restrict__ trans,
        const float* __restrict__ startt,
        const float* __restrict__ endt,
        float* __restrict__ gold)
{
    __shared__ float red[256];
    const int b = blockIdx.x, tid = threadIdx.x;
    float local = 0.f;
    for (int t = tid; t < SS; t += 256) {
        const int tg = tags[b * SS + t];
        float v = em[(size_t)(b * SS + t) * TT + tg];
        if (t > 0) v += trans[tg * TT + tags[b * SS + t - 1]];  // trans[next, prev] per reference
        else       v += startt[tg];
        if (t == SS - 1) v += endt[tg];                          // mask all-true -> last = S-1
        local += v;
    }
    red[tid] = local; __syncthreads();
    for (int s = 128; s > 0; s >>= 1) { if (tid < s) red[tid] += red[tid + s]; __syncthreads(); }
    if (tid == 0) gold[b] = red[0];
}

// ---------------- Final reduction: mean(logZ - gold) ----------------
__global__ __launch_bounds__(256) void final_kernel(
        const float* __restrict__ logZ,
        const float* __restrict__ gold,
        float* __restrict__ out)
{
    __shared__ float red[256];
    const int tid = threadIdx.x;
    float local = 0.f;
    for (int b = tid; b < BB; b += 256) local += logZ[b] - gold[b];
    red[tid] = local; __syncthreads();
    for (int s = 128; s > 0; s >>= 1) { if (tid < s) red[tid] += red[tid + s]; __syncthreads(); }
    if (tid == 0) out[0] = red[0] * (1.0f / BB);
}

extern "C" void kernel_launch(void* const* d_in, const int* in_sizes, int n_in,
                              void* d_out, int out_size, void* d_ws, size_t ws_size,
                              hipStream_t stream) {
    const float* em     = (const float*)d_in[0];   // (B,S,T) fp32
    const int*   tags   = (const int*)  d_in[1];   // (B,S) int32
    // d_in[2] = mask, all ones -> ignored
    const float* trans  = (const float*)d_in[3];   // (T,T)
    const float* startt = (const float*)d_in[4];   // (T,)
    const float* endt   = (const float*)d_in[5];   // (T,)
    float* out = (float*)d_out;

    // workspace carve-up (~16.9 MB)
    float* mats   = (float*)d_ws;                                  // B*C*256 fp32 = 16 MB
    int*   scales = (int*)((char*)d_ws + (size_t)BB * CC * 256 * 4);
    float* logZ   = (float*)((char*)scales + (size_t)BB * CC * 4);
    float* gold   = logZ + BB;

    phase1_kernel<<<BB * CC / 4, 256, 0, stream>>>(em, trans, mats, scales);
    gold_kernel  <<<BB,          256, 0, stream>>>(em, tags, trans, startt, endt, gold);
    phase2_kernel<<<BB / 16,     256, 0, stream>>>(em, startt, endt, mats, scales, logZ);
    final_kernel <<<1,           256, 0, stream>>>(logZ, gold, out);
}

// Round 2
// 166.259 us; speedup vs baseline: 1.1832x; 1.1832x over previous
//
#include <hip/hip_runtime.h>
#include <stdint.h>

// CRF mean-NLL, B=1024 S=1024 T=16.
// logZ via exp-domain linear recurrence: u_t = N_t u_{t-1}, N_t = diag(exp(em_t)) * exp(trans)^T.
// Phase 1: 16 chunks of 64 steps per batch; each wave builds P_c = prod N_t via bf16 MFMA
//          16x16x16 (D layout == next B-operand layout). Power-of-2 rescale every 8 steps.
//          bf16 pack = v_perm_b32 (3 instrs, round-half-up). Unroll-8 + block-preloaded loads.
// Phase 2: per batch, 16 sequential 16x16 matvecs fp32 + log-domain scale accumulation,
//          fused with final mean(logZ-gold) via atomicAdd (d_out memset to 0 first).

#define BB 1024
#define SS 1024
#define TT 16
#define CC 16   // chunks per batch
#define LL 64   // steps per chunk

typedef float  f32x4 __attribute__((ext_vector_type(4)));
typedef short  s16x4 __attribute__((ext_vector_type(4)));
typedef uint32_t u32x2 __attribute__((ext_vector_type(2)));

// round-half-up f32->bf16 pack of (lo,hi) into one dword via v_perm_b32
__device__ __forceinline__ uint32_t pk(float lo, float hi) {
    return __builtin_amdgcn_perm(__float_as_uint(hi) + 0x8000u,
                                 __float_as_uint(lo) + 0x8000u, 0x07060302u);
}

__device__ __forceinline__ s16x4 mk_frag(uint32_t lo, uint32_t hi) {
    u32x2 t; t.x = lo; t.y = hi;
    return __builtin_bit_cast(s16x4, t);
}

// ---------------- Phase 1: chunk matrix products ----------------
__global__ __launch_bounds__(256) void phase1_kernel(
        const float* __restrict__ em,      // (B,S,T)
        const float* __restrict__ trans,   // (T,T)
        float* __restrict__ mats,          // (B*C, 256)
        int*   __restrict__ scales)        // (B*C)
{
    const int wave = threadIdx.x >> 6;
    const int lane = threadIdx.x & 63;
    const int id   = blockIdx.x * 4 + wave;   // 0 .. B*C-1
    const int b    = id >> 4;
    const int c    = id & 15;
    const int q    = lane >> 4;               // quad
    const int m    = lane & 15;

    // A-operand constants: N_t[m][4q+j] = x_t[m] * exp(trans[4q+j][m])
    const float e0 = __expf(trans[(4*q + 0) * TT + m]);
    const float e1 = __expf(trans[(4*q + 1) * TT + m]);
    const float e2 = __expf(trans[(4*q + 2) * TT + m]);
    const float e3 = __expf(trans[(4*q + 3) * TT + m]);

    // running product in fp32 D layout: d[r] = P[4q+r][m]; starts as identity
    f32x4 d;
    d[0] = (4*q + 0 == m) ? 1.f : 0.f;
    d[1] = (4*q + 1 == m) ? 1.f : 0.f;
    d[2] = (4*q + 2 == m) ? 1.f : 0.f;
    d[3] = (4*q + 3 == m) ? 1.f : 0.f;
    const f32x4 zero = {0.f, 0.f, 0.f, 0.f};
    int sc = 0;

    const int t0 = (c == 0) ? 1 : c * LL;     // forward steps are t = 1 .. S-1
    const float* ep = em + (size_t)b * SS * TT + (size_t)t0 * TT + m;

#define STEP(xv) {                                                        \
        const s16x4 bf = mk_frag(pk(d[0], d[1]), pk(d[2], d[3]));         \
        const float x_ = (xv);                                            \
        const s16x4 af = mk_frag(pk(x_ * e0, x_ * e1), pk(x_ * e2, x_ * e3)); \
        d = __builtin_amdgcn_mfma_f32_16x16x16bf16_1k(af, bf, zero, 0, 0, 0); }

#define RESCALE() {                                                       \
        float mx = fmaxf(fmaxf(d[0], d[1]), fmaxf(d[2], d[3]));           \
        _Pragma("unroll")                                                 \
        for (int s_ = 1; s_ < 64; s_ <<= 1) mx = fmaxf(mx, __shfl_xor(mx, s_, 64)); \
        const int e_ = (int)(__float_as_uint(mx) >> 23) - 127;            \
        const float sf_ = __uint_as_float((uint32_t)(127 - e_) << 23);    \
        d[0] *= sf_; d[1] *= sf_; d[2] *= sf_; d[3] *= sf_;               \
        sc += e_; }

    if (c == 0) {                             // peel t = 1..7 (7 steps)
        #pragma unroll
        for (int i = 0; i < 7; ++i) { STEP(__expf(ep[0])); ep += TT; }
        RESCALE();
    }

    const int nb = (c == 0) ? 7 : 8;          // remaining blocks of 8 steps
    for (int bb = 0; bb < nb; ++bb) {
        float xr[8];
        #pragma unroll
        for (int i = 0; i < 8; ++i) xr[i] = ep[i * TT];   // 8 loads in flight
        ep += 8 * TT;
        #pragma unroll
        for (int i = 0; i < 8; ++i) STEP(__expf(xr[i]));
        RESCALE();
    }
#undef STEP
#undef RESCALE

    // store P_c (fp32): D reg r -> P[4q+r][m]
    float* mp = mats + (size_t)id * 256;
    mp[(4*q + 0) * TT + m] = d[0];
    mp[(4*q + 1) * TT + m] = d[1];
    mp[(4*q + 2) * TT + m] = d[2];
    mp[(4*q + 3) * TT + m] = d[3];
    if (lane == 0) scales[id] = sc;
}

// ---------------- Phase 2: sequential chunk combine + final reduce ----------------
__global__ __launch_bounds__(64) void phase2_kernel(
        const float* __restrict__ em,
        const float* __restrict__ startt,
        const float* __restrict__ endt,
        const float* __restrict__ mats,
        const int*   __restrict__ scales,
        const float* __restrict__ gold,
        float* __restrict__ out)
{
    const int lane = threadIdx.x;             // one wave per block
    const int g    = lane >> 4;               // 4 batches per wave
    const int m    = lane & 15;
    const int b    = blockIdx.x * 4 + g;
    const int base = lane & 48;

    // u0 = exp(start + em[:,0] - max)
    const float s0 = startt[m] + em[(size_t)b * SS * TT + m];
    float mx = s0;
    #pragma unroll
    for (int s = 1; s < 16; s <<= 1) mx = fmaxf(mx, __shfl_xor(mx, s, 16));
    float u   = __expf(s0 - mx);
    float ell = mx;

    for (int c = 0; c < CC; ++c) {
        const float* row = mats + (size_t)(b * CC + c) * 256 + m * TT;
        const f32x4 r0 = *(const f32x4*)(row + 0);
        const f32x4 r1 = *(const f32x4*)(row + 4);
        const f32x4 r2 = *(const f32x4*)(row + 8);
        const f32x4 r3 = *(const f32x4*)(row + 12);
        float acc = 0.f;
        #pragma unroll
        for (int k = 0; k < 4; ++k) acc += r0[k] * __shfl(u, base + k,      64);
        #pragma unroll
        for (int k = 0; k < 4; ++k) acc += r1[k] * __shfl(u, base + 4 + k,  64);
        #pragma unroll
        for (int k = 0; k < 4; ++k) acc += r2[k] * __shfl(u, base + 8 + k,  64);
        #pragma unroll
        for (int k = 0; k < 4; ++k) acc += r3[k] * __shfl(u, base + 12 + k, 64);

        float m2 = acc;
        #pragma unroll
        for (int s = 1; s < 16; s <<= 1) m2 = fmaxf(m2, __shfl_xor(m2, s, 16));
        u = acc / m2;
        ell += __logf(m2) + (float)scales[b * CC + c] * 0.6931471805599453f;
    }

    float v = u * __expf(endt[m]);
    #pragma unroll
    for (int s = 1; s < 16; s <<= 1) v += __shfl_xor(v, s, 16);

    float contrib = (m == 0) ? (ell + __logf(v) - gold[b]) : 0.f;
    #pragma unroll
    for (int s = 1; s < 64; s <<= 1) contrib += __shfl_xor(contrib, s, 64);
    if (lane == 0) atomicAdd(out, contrib * (1.0f / BB));
}

// ---------------- Gold score ----------------
__global__ __launch_bounds__(256) void gold_kernel(
        const float* __restrict__ em,
        const int*   __restrict__ tags,    // int32
        const float* __restrict__ trans,
        const float* __restrict__ startt,
        const float* __restrict__ endt,
        float* __restrict__ gold)
{
    __shared__ float red[256];
    const int b = blockIdx.x, tid = threadIdx.x;
    float local = 0.f;
    for (int t = tid; t < SS; t += 256) {
        const int tg = tags[b * SS + t];
        float v = em[(size_t)(b * SS + t) * TT + tg];
        if (t > 0) v += trans[tg * TT + tags[b * SS + t - 1]];  // trans[next, prev]
        else       v += startt[tg];
        if (t == SS - 1) v += endt[tg];                          // mask all-true
        local += v;
    }
    red[tid] = local; __syncthreads();
    for (int s = 128; s > 0; s >>= 1) { if (tid < s) red[tid] += red[tid + s]; __syncthreads(); }
    if (tid == 0) gold[b] = red[0];
}

extern "C" void kernel_launch(void* const* d_in, const int* in_sizes, int n_in,
                              void* d_out, int out_size, void* d_ws, size_t ws_size,
                              hipStream_t stream) {
    const float* em     = (const float*)d_in[0];   // (B,S,T) fp32
    const int*   tags   = (const int*)  d_in[1];   // (B,S) int32
    // d_in[2] = mask, all ones -> ignored
    const float* trans  = (const float*)d_in[3];   // (T,T)
    const float* startt = (const float*)d_in[4];   // (T,)
    const float* endt   = (const float*)d_in[5];   // (T,)
    float* out = (float*)d_out;

    float* mats   = (float*)d_ws;                                  // B*C*256 fp32 = 16 MB
    int*   scales = (int*)((char*)d_ws + (size_t)BB * CC * 256 * 4);
    float* gold   = (float*)((char*)scales + (size_t)BB * CC * 4);

    hipMemsetAsync(out, 0, sizeof(float), stream);
    phase1_kernel<<<BB * CC / 4, 256, 0, stream>>>(em, trans, mats, scales);
    gold_kernel  <<<BB,          256, 0, stream>>>(em, tags, trans, startt, endt, gold);
    phase2_kernel<<<BB / 4,       64, 0, stream>>>(em, startt, endt, mats, scales, gold, out);
}

// Round 3
// 145.727 us; speedup vs baseline: 1.3499x; 1.1409x over previous
//
#include <hip/hip_runtime.h>
#include <stdint.h>

// CRF mean-NLL, B=1024 S=1024 T=16.
// logZ via exp-domain linear recurrence: u_t = N_t u_{t-1}, N_t = diag(exp(em_t)) * exp(trans)^T.
// Fused1: blocks [0,4096) = phase1 (chunk matrix products, bf16 MFMA 16x16x16, D->B feedback),
//         blocks [4096,5120) = gold score. Phase1 hot loop: truncation bf16 pack (1 v_perm/pair,
//         bias folded into e_j consts), one exp per lane per 4 steps (bpermute broadcast),
//         per-COLUMN power-of-2 rescale every 8 steps (2 shuffles, exact int exponents).
// Phase2: per batch 16 sequential 16x16 matvecs fp32, per-column scales folded via ldexp,
//         fused final mean(logZ-gold) via atomicAdd (out memset to 0 first).

#define BB 1024
#define SS 1024
#define TT 16
#define CC 16
#define LL 64
#define P1B (BB * CC / 4)   // 4096 phase1 blocks

typedef float    f32x4 __attribute__((ext_vector_type(4)));
typedef float    f32x2 __attribute__((ext_vector_type(2)));
typedef short    s16x4 __attribute__((ext_vector_type(4)));
typedef uint32_t u32x2 __attribute__((ext_vector_type(2)));

// truncating f32->bf16 pack of (lo,hi) into one dword: single v_perm_b32
__device__ __forceinline__ uint32_t pkt(float lo, float hi) {
    return __builtin_amdgcn_perm(__float_as_uint(hi), __float_as_uint(lo), 0x07060302u);
}
__device__ __forceinline__ s16x4 mk_frag(uint32_t lo, uint32_t hi) {
    u32x2 t; t.x = lo; t.y = hi;
    return __builtin_bit_cast(s16x4, t);
}

__global__ __launch_bounds__(256) void fused1_kernel(
        const float* __restrict__ em,      // (B,S,T)
        const float* __restrict__ trans,   // (T,T)
        const int*   __restrict__ tags,    // (B,S) int32
        const float* __restrict__ startt,  // (T)
        const float* __restrict__ endt,    // (T)
        float* __restrict__ mats,          // (B*C,256)
        int*   __restrict__ scales,        // (B*C,16) per-column exponents
        float* __restrict__ gold)          // (B)
{
    __shared__ float red[256];
    if (blockIdx.x < P1B) {
        // ---------------- phase 1 ----------------
        const int wave = threadIdx.x >> 6;
        const int lane = threadIdx.x & 63;
        const int id   = blockIdx.x * 4 + wave;   // (b,c)
        const int b    = id >> 4;
        const int c    = id & 15;
        const int q    = lane >> 4;
        const int m    = lane & 15;

        // A-operand row constants, truncation-compensated: (1+2^-9)^2 ~= 1.00390625
        const float comp = 1.00390625f;
        f32x2 e01, e23;
        e01.x = __expf(trans[(4*q + 0) * TT + m]) * comp;
        e01.y = __expf(trans[(4*q + 1) * TT + m]) * comp;
        e23.x = __expf(trans[(4*q + 2) * TT + m]) * comp;
        e23.y = __expf(trans[(4*q + 3) * TT + m]) * comp;

        // running product, D layout: d[r] = P[4q+r][m]; identity start
        f32x4 d;
        d[0] = (4*q + 0 == m) ? 1.f : 0.f;
        d[1] = (4*q + 1 == m) ? 1.f : 0.f;
        d[2] = (4*q + 2 == m) ? 1.f : 0.f;
        d[3] = (4*q + 3 == m) ? 1.f : 0.f;
        const f32x4 zero = {0.f, 0.f, 0.f, 0.f};
        int sc = 0;

        // lane (q,m) loads em row (tb+q), col m: addr = base + tb*16 + lane (coalesced)
        const float* ep = em + (size_t)b * SS * TT + (size_t)(c * LL) * TT + lane;

#define STEP(xv) {                                                          \
        const s16x4 bfr = mk_frag(pkt(d[0], d[1]), pkt(d[2], d[3]));        \
        f32x2 xx; xx.x = (xv); xx.y = (xv);                                 \
        const f32x2 a01 = xx * e01;                                         \
        const f32x2 a23 = xx * e23;                                         \
        const s16x4 afr = mk_frag(pkt(a01.x, a01.y), pkt(a23.x, a23.y));    \
        d = __builtin_amdgcn_mfma_f32_16x16x16bf16_1k(afr, bfr, zero, 0, 0, 0); }

#define SUB4(exv, P0) { _Pragma("unroll")                                   \
        for (int p = (P0); p < 4; ++p) {                                    \
            const float xp = __shfl((exv), p * 16 + m, 64);                 \
            STEP(xp); } }

#define RESCALE() {                                                         \
        float mx = fmaxf(fmaxf(d[0], d[1]), fmaxf(d[2], d[3]));             \
        mx = fmaxf(mx, __shfl_xor(mx, 16, 64));                             \
        mx = fmaxf(mx, __shfl_xor(mx, 32, 64));                             \
        const int e_ = (int)(__float_as_uint(mx) >> 23) - 127;              \
        const float sf_ = __uint_as_float((uint32_t)(127 - e_) << 23);      \
        d[0] *= sf_; d[1] *= sf_; d[2] *= sf_; d[3] *= sf_;                 \
        sc += e_; }

#define BLK8(P0) {                                                          \
        const float x0_ = ep[0];                                            \
        const float x1_ = ep[64];                                           \
        ep += 128;                                                          \
        const float ex0_ = __expf(x0_);                                     \
        const float ex1_ = __expf(x1_);                                     \
        SUB4(ex0_, P0);                                                     \
        SUB4(ex1_, 0);                                                      \
        RESCALE(); }

        if (c == 0) { BLK8(1); }                  // steps t=1..7
        const int nb = (c == 0) ? 7 : 8;
        for (int bbk = 0; bbk < nb; ++bbk) { BLK8(0); }
#undef STEP
#undef SUB4
#undef RESCALE
#undef BLK8

        float* mp = mats + (size_t)id * 256;
        mp[(4*q + 0) * TT + m] = d[0];
        mp[(4*q + 1) * TT + m] = d[1];
        mp[(4*q + 2) * TT + m] = d[2];
        mp[(4*q + 3) * TT + m] = d[3];
        if (q == 0) scales[id * 16 + m] = sc;     // per-column exponent
    } else {
        // ---------------- gold score ----------------
        const int b = blockIdx.x - P1B, tid = threadIdx.x;
        float local = 0.f;
        for (int t = tid; t < SS; t += 256) {
            const int tg = tags[b * SS + t];
            float v = em[(size_t)(b * SS + t) * TT + tg];
            if (t > 0) v += trans[tg * TT + tags[b * SS + t - 1]];  // trans[next, prev]
            else       v += startt[tg];
            if (t == SS - 1) v += endt[tg];                          // mask all-true
            local += v;
        }
        red[tid] = local; __syncthreads();
        for (int s = 128; s > 0; s >>= 1) { if (tid < s) red[tid] += red[tid + s]; __syncthreads(); }
        if (tid == 0) gold[b] = red[0];
    }
}

// ---------------- Phase 2: sequential chunk combine + final reduce ----------------
__global__ __launch_bounds__(64) void phase2_kernel(
        const float* __restrict__ em,
        const float* __restrict__ startt,
        const float* __restrict__ endt,
        const float* __restrict__ mats,
        const int*   __restrict__ scales,
        const float* __restrict__ gold,
        float* __restrict__ out)
{
    const int lane = threadIdx.x;             // one wave per block
    const int g    = lane >> 4;               // 4 batches per wave
    const int m    = lane & 15;
    const int b    = blockIdx.x * 4 + g;
    const int base = lane & 48;

    // u0 = exp(start + em[:,0] - max)
    const float s0 = startt[m] + em[(size_t)b * SS * TT + m];
    float mx = s0;
    #pragma unroll
    for (int s = 1; s < 16; s <<= 1) mx = fmaxf(mx, __shfl_xor(mx, s, 16));
    float u   = __expf(s0 - mx);
    float ell = mx;

    for (int c = 0; c < CC; ++c) {
        const int idc = b * CC + c;
        int scm = scales[idc * 16 + m];
        int smax = scm;
        #pragma unroll
        for (int s = 1; s < 16; s <<= 1) smax = max(smax, __shfl_xor(smax, s, 16));
        const float up = ldexpf(u, scm - smax);   // fold per-column exponent (spread <= ~18 bits)

        const float* row = mats + (size_t)idc * 256 + m * TT;
        const f32x4 r0 = *(const f32x4*)(row + 0);
        const f32x4 r1 = *(const f32x4*)(row + 4);
        const f32x4 r2 = *(const f32x4*)(row + 8);
        const f32x4 r3 = *(const f32x4*)(row + 12);
        float acc = 0.f;
        #pragma unroll
        for (int k = 0; k < 4; ++k) acc += r0[k] * __shfl(up, base + k,      64);
        #pragma unroll
        for (int k = 0; k < 4; ++k) acc += r1[k] * __shfl(up, base + 4 + k,  64);
        #pragma unroll
        for (int k = 0; k < 4; ++k) acc += r2[k] * __shfl(up, base + 8 + k,  64);
        #pragma unroll
        for (int k = 0; k < 4; ++k) acc += r3[k] * __shfl(up, base + 12 + k, 64);

        float m2 = acc;
        #pragma unroll
        for (int s = 1; s < 16; s <<= 1) m2 = fmaxf(m2, __shfl_xor(m2, s, 16));
        u = acc / m2;
        ell += __logf(m2) + (float)smax * 0.6931471805599453f;
    }

    float v = u * __expf(endt[m]);
    #pragma unroll
    for (int s = 1; s < 16; s <<= 1) v += __shfl_xor(v, s, 16);

    float contrib = (m == 0) ? (ell + __logf(v) - gold[b]) : 0.f;
    #pragma unroll
    for (int s = 1; s < 64; s <<= 1) contrib += __shfl_xor(contrib, s, 64);
    if (lane == 0) atomicAdd(out, contrib * (1.0f / BB));
}

extern "C" void kernel_launch(void* const* d_in, const int* in_sizes, int n_in,
                              void* d_out, int out_size, void* d_ws, size_t ws_size,
                              hipStream_t stream) {
    const float* em     = (const float*)d_in[0];   // (B,S,T) fp32
    const int*   tags   = (const int*)  d_in[1];   // (B,S) int32
    // d_in[2] = mask, all ones -> ignored
    const float* trans  = (const float*)d_in[3];   // (T,T)
    const float* startt = (const float*)d_in[4];   // (T,)
    const float* endt   = (const float*)d_in[5];   // (T,)
    float* out = (float*)d_out;

    float* mats   = (float*)d_ws;                                          // 16 MB
    int*   scales = (int*)((char*)d_ws + (size_t)BB * CC * 256 * 4);       // 1 MB
    float* gold   = (float*)((char*)scales + (size_t)BB * CC * 16 * 4);    // 4 KB

    hipMemsetAsync(out, 0, sizeof(float), stream);
    fused1_kernel<<<P1B + BB, 256, 0, stream>>>(em, trans, tags, startt, endt, mats, scales, gold);
    phase2_kernel<<<BB / 4, 64, 0, stream>>>(em, startt, endt, mats, scales, gold, out);
}

// Round 4
// 142.489 us; speedup vs baseline: 1.3806x; 1.0227x over previous
//
#include <hip/hip_runtime.h>
#include <stdint.h>

// CRF mean-NLL, B=1024 S=1024 T=16.
// logZ via exp-domain linear recurrence: u_t = N_t u_{t-1}, N_t = diag(exp(em_t)) * exp(trans)^T.
// fused1: blocks [0,4096) = phase1 chunk matrix products (bf16 MFMA 16x16x16, D->B feedback,
//         per-column power-of-2 rescale every 8 steps); blocks [4096,5120) = gold score.
//         Broadcast of exp(em) via explicit ds_bpermute, 8 issued per block BEFORE the 8
//         dependent MFMA steps (one lgkm wait per 8 steps, no per-call index math).
// combine: 1 wave per batch; 15 sequential MFMA matrix products over the 16 chunk mats
//          (exact per-column scale algebra: row-scale B by 2^(s_c - max s_c) via v_ldexp,
//          scalar max into gamma, column rescale into sigma), then u0/end epilogue.
//          Fused final mean(logZ-gold) via atomicAdd (out memset to 0 first).

#define BB 1024
#define SS 1024
#define TT 16
#define CC 16
#define LL 64
#define P1B (BB * CC / 4)   // 4096 phase1 blocks

typedef float    f32x4 __attribute__((ext_vector_type(4)));
typedef float    f32x2 __attribute__((ext_vector_type(2)));
typedef int      i32x4 __attribute__((ext_vector_type(4)));
typedef short    s16x4 __attribute__((ext_vector_type(4)));
typedef uint32_t u32x2 __attribute__((ext_vector_type(2)));

// truncating f32->bf16 pack of (lo,hi) into one dword: single v_perm_b32
__device__ __forceinline__ uint32_t pkt(float lo, float hi) {
    return __builtin_amdgcn_perm(__float_as_uint(hi), __float_as_uint(lo), 0x07060302u);
}
__device__ __forceinline__ s16x4 mk_frag(uint32_t lo, uint32_t hi) {
    u32x2 t; t.x = lo; t.y = hi;
    return __builtin_bit_cast(s16x4, t);
}

__global__ __launch_bounds__(256) void fused1_kernel(
        const float* __restrict__ em,      // (B,S,T)
        const float* __restrict__ trans,   // (T,T)
        const int*   __restrict__ tags,    // (B,S) int32
        const float* __restrict__ startt,  // (T)
        const float* __restrict__ endt,    // (T)
        float* __restrict__ mats,          // (B*C,256)
        int*   __restrict__ scales,        // (B*C,16) per-column exponents
        float* __restrict__ gold)          // (B)
{
    __shared__ float red[256];
    if (blockIdx.x < P1B) {
        // ---------------- phase 1 ----------------
        const int wave = threadIdx.x >> 6;
        const int lane = threadIdx.x & 63;
        const int id   = blockIdx.x * 4 + wave;   // (b,c)
        const int b    = id >> 4;
        const int c    = id & 15;
        const int q    = lane >> 4;
        const int m    = lane & 15;

        // hoisted ds_bpermute byte addresses: source lanes p*16+m
        const int bpa0 = (m +  0) << 2;
        const int bpa1 = (m + 16) << 2;
        const int bpa2 = (m + 32) << 2;
        const int bpa3 = (m + 48) << 2;

        // A-operand row constants, truncation-compensated: (1+2^-9)^2 ~= 1.00390625
        const float comp = 1.00390625f;
        f32x2 e01, e23;
        e01.x = __expf(trans[(4*q + 0) * TT + m]) * comp;
        e01.y = __expf(trans[(4*q + 1) * TT + m]) * comp;
        e23.x = __expf(trans[(4*q + 2) * TT + m]) * comp;
        e23.y = __expf(trans[(4*q + 3) * TT + m]) * comp;

        // running product, D layout: d[r] = P[4q+r][m]; identity start
        f32x4 d;
        d[0] = (4*q + 0 == m) ? 1.f : 0.f;
        d[1] = (4*q + 1 == m) ? 1.f : 0.f;
        d[2] = (4*q + 2 == m) ? 1.f : 0.f;
        d[3] = (4*q + 3 == m) ? 1.f : 0.f;
        const f32x4 zero = {0.f, 0.f, 0.f, 0.f};
        int sc = 0;

        // lane (q,m) loads em row (tb+q), col m: addr = base + tb*16 + lane (coalesced)
        const float* ep = em + (size_t)b * SS * TT + (size_t)(c * LL) * TT + lane;

#define STEP(xv) {                                                          \
        const s16x4 bfr = mk_frag(pkt(d[0], d[1]), pkt(d[2], d[3]));        \
        f32x2 xx; xx.x = (xv); xx.y = (xv);                                 \
        const f32x2 a01 = xx * e01;                                         \
        const f32x2 a23 = xx * e23;                                         \
        const s16x4 afr = mk_frag(pkt(a01.x, a01.y), pkt(a23.x, a23.y));    \
        d = __builtin_amdgcn_mfma_f32_16x16x16bf16_1k(afr, bfr, zero, 0, 0, 0); }

#define RESCALE() {                                                         \
        float mx = fmaxf(fmaxf(d[0], d[1]), fmaxf(d[2], d[3]));             \
        mx = fmaxf(mx, __shfl_xor(mx, 16, 64));                             \
        mx = fmaxf(mx, __shfl_xor(mx, 32, 64));                             \
        const int e_ = (int)(__float_as_uint(mx) >> 23) - 127;              \
        const float sf_ = __uint_as_float((uint32_t)(127 - e_) << 23);      \
        d[0] *= sf_; d[1] *= sf_; d[2] *= sf_; d[3] *= sf_;                 \
        sc += e_; }

        // all 8 broadcasts issued up-front, then 8 dependent MFMA steps
#define BLK8(P0) {                                                          \
        const float x0_ = ep[0];                                            \
        const float x1_ = ep[64];                                           \
        ep += 128;                                                          \
        const int ei0 = __float_as_int(__expf(x0_));                        \
        const int ei1 = __float_as_int(__expf(x1_));                        \
        float xp[8];                                                        \
        xp[0] = __int_as_float(__builtin_amdgcn_ds_bpermute(bpa0, ei0));    \
        xp[1] = __int_as_float(__builtin_amdgcn_ds_bpermute(bpa1, ei0));    \
        xp[2] = __int_as_float(__builtin_amdgcn_ds_bpermute(bpa2, ei0));    \
        xp[3] = __int_as_float(__builtin_amdgcn_ds_bpermute(bpa3, ei0));    \
        xp[4] = __int_as_float(__builtin_amdgcn_ds_bpermute(bpa0, ei1));    \
        xp[5] = __int_as_float(__builtin_amdgcn_ds_bpermute(bpa1, ei1));    \
        xp[6] = __int_as_float(__builtin_amdgcn_ds_bpermute(bpa2, ei1));    \
        xp[7] = __int_as_float(__builtin_amdgcn_ds_bpermute(bpa3, ei1));    \
        _Pragma("unroll")                                                   \
        for (int i = (P0); i < 8; ++i) { STEP(xp[i]); }                     \
        RESCALE(); }

        if (c == 0) { BLK8(1); }                  // steps t=1..7
        const int nb = (c == 0) ? 7 : 8;
        for (int bbk = 0; bbk < nb; ++bbk) { BLK8(0); }
#undef STEP
#undef RESCALE
#undef BLK8

        float* mp = mats + (size_t)id * 256;
        mp[(4*q + 0) * TT + m] = d[0];
        mp[(4*q + 1) * TT + m] = d[1];
        mp[(4*q + 2) * TT + m] = d[2];
        mp[(4*q + 3) * TT + m] = d[3];
        if (q == 0) scales[id * 16 + m] = sc;     // per-column exponent
    } else {
        // ---------------- gold score ----------------
        const int b = blockIdx.x - P1B, tid = threadIdx.x;
        float local = 0.f;
        for (int t = tid; t < SS; t += 256) {
            const int tg = tags[b * SS + t];
            float v = em[(size_t)(b * SS + t) * TT + tg];
            if (t > 0) v += trans[tg * TT + tags[b * SS + t - 1]];  // trans[next, prev]
            else       v += startt[tg];
            if (t == SS - 1) v += endt[tg];                          // mask all-true
            local += v;
        }
        red[tid] = local; __syncthreads();
        for (int s = 128; s > 0; s >>= 1) { if (tid < s) red[tid] += red[tid + s]; __syncthreads(); }
        if (tid == 0) gold[b] = red[0];
    }
}

// ---------------- combine: MFMA chunk-product + epilogue + final reduce ----------------
__global__ __launch_bounds__(256) void combine_kernel(
        const float* __restrict__ em,
        const float* __restrict__ startt,
        const float* __restrict__ endt,
        const float* __restrict__ mats,
        const int*   __restrict__ scales,
        const float* __restrict__ gold,
        float* __restrict__ out)
{
    const int wave = threadIdx.x >> 6;
    const int lane = threadIdx.x & 63;
    const int b    = blockIdx.x * 4 + wave;   // one wave per batch
    const int q    = lane >> 4;
    const int m    = lane & 15;

    // init from chunk 0: d[r] = M_0[4q+r][m]; sigma = s_0[m]; gamma = 0
    const float* m0 = mats + (size_t)(b * CC) * 256;
    f32x4 d;
    d[0] = m0[(4*q + 0) * TT + m];
    d[1] = m0[(4*q + 1) * TT + m];
    d[2] = m0[(4*q + 2) * TT + m];
    d[3] = m0[(4*q + 3) * TT + m];
    int sig = scales[(b * CC) * 16 + m];
    int gam = 0;
    const f32x4 zero = {0.f, 0.f, 0.f, 0.f};

    #pragma unroll 4
    for (int c = 1; c < CC; ++c) {
        const int idc = b * CC + c;
        // A = M_c in A-layout: A[m][4q+j] -> contiguous f32x4
        const f32x4 a = *(const f32x4*)(mats + (size_t)idc * 256 + m * TT + 4 * q);
        // row scales s_c[4q+j], contiguous int4
        const i32x4 s = *(const i32x4*)(scales + idc * 16 + 4 * q);
        int sm = max(max(s.x, s.y), max(s.z, s.w));
        sm = max(sm, __shfl_xor(sm, 16, 64));
        sm = max(sm, __shfl_xor(sm, 32, 64));
        // B = diag(2^(s_c - sm)) * D_cur, bf16 (exponents <= 0, range-safe)
        const float r0 = ldexpf(d[0], s.x - sm);
        const float r1 = ldexpf(d[1], s.y - sm);
        const float r2 = ldexpf(d[2], s.z - sm);
        const float r3 = ldexpf(d[3], s.w - sm);
        const s16x4 bfr = mk_frag(pkt(r0, r1), pkt(r2, r3));
        const s16x4 afr = mk_frag(pkt(a.x, a.y), pkt(a.z, a.w));
        d = __builtin_amdgcn_mfma_f32_16x16x16bf16_1k(afr, bfr, zero, 0, 0, 0);
        gam += sm;
        // column rescale
        float mx = fmaxf(fmaxf(d[0], d[1]), fmaxf(d[2], d[3]));
        mx = fmaxf(mx, __shfl_xor(mx, 16, 64));
        mx = fmaxf(mx, __shfl_xor(mx, 32, 64));
        const int e = (int)(__float_as_uint(mx) >> 23) - 127;
        const float sf = __uint_as_float((uint32_t)(127 - e) << 23);
        d[0] *= sf; d[1] *= sf; d[2] *= sf; d[3] *= sf;
        sig += e;
    }

    // ---- epilogue: logZ = mx0 + ln2*(gam + sigmax) + log( end^T * V * w ) ----
    const float s0 = startt[m] + em[(size_t)b * SS * TT + m];
    float mx0 = s0;
    #pragma unroll
    for (int s = 1; s < 16; s <<= 1) mx0 = fmaxf(mx0, __shfl_xor(mx0, s, 64));
    const float u0n = __expf(s0 - mx0);

    int sigmax = sig;
    #pragma unroll
    for (int s = 1; s < 16; s <<= 1) sigmax = max(sigmax, __shfl_xor(sigmax, s, 64));
    const float w = ldexpf(u0n, sig - sigmax);     // per-column weight

    f32x4 v;
    v[0] = d[0] * w; v[1] = d[1] * w; v[2] = d[2] * w; v[3] = d[3] * w;
    #pragma unroll
    for (int s = 1; s < 16; s <<= 1) {
        v[0] += __shfl_xor(v[0], s, 64);
        v[1] += __shfl_xor(v[1], s, 64);
        v[2] += __shfl_xor(v[2], s, 64);
        v[3] += __shfl_xor(v[3], s, 64);
    }
    const f32x4 ee = *(const f32x4*)(endt + 4 * q);
    float z = __expf(ee.x) * v[0] + __expf(ee.y) * v[1]
            + __expf(ee.z) * v[2] + __expf(ee.w) * v[3];
    z += __shfl_xor(z, 16, 64);
    z += __shfl_xor(z, 32, 64);

    if (lane == 0) {
        const float logZ = mx0 + 0.69314718055994531f * (float)(gam + sigmax) + __logf(z);
        atomicAdd(out, (logZ - gold[b]) * (1.0f / BB));
    }
}

extern "C" void kernel_launch(void* const* d_in, const int* in_sizes, int n_in,
                              void* d_out, int out_size, void* d_ws, size_t ws_size,
                              hipStream_t stream) {
    const float* em     = (const float*)d_in[0];   // (B,S,T) fp32
    const int*   tags   = (const int*)  d_in[1];   // (B,S) int32
    // d_in[2] = mask, all ones -> ignored
    const float* trans  = (const float*)d_in[3];   // (T,T)
    const float* startt = (const float*)d_in[4];   // (T,)
    const float* endt   = (const float*)d_in[5];   // (T,)
    float* out = (float*)d_out;

    float* mats   = (float*)d_ws;                                          // 16 MB
    int*   scales = (int*)((char*)d_ws + (size_t)BB * CC * 256 * 4);       // 1 MB
    float* gold   = (float*)((char*)scales + (size_t)BB * CC * 16 * 4);    // 4 KB

    hipMemsetAsync(out, 0, sizeof(float), stream);
    fused1_kernel<<<P1B + BB, 256, 0, stream>>>(em, trans, tags, startt, endt, mats, scales, gold);
    combine_kernel<<<BB / 4, 256, 0, stream>>>(em, startt, endt, mats, scales, gold, out);
}

// Round 5
// 140.444 us; speedup vs baseline: 1.4007x; 1.0146x over previous
//
#include <hip/hip_runtime.h>
#include <stdint.h>

// CRF mean-NLL, B=1024 S=1024 T=16.
// logZ via exp-domain linear recurrence: u_t = N_t u_{t-1}, N_t = diag(x_t)*E, E = exp(trans)^T.
// Reassociated so the MFMA A-operand is the CONSTANT E (packed once per wave):
//   P <- diag(x_t) * (E * P);  diag fold happens in the next B-pack (sd = d_raw .* xr).
// x_t[4q..4q+3] per lane comes from a per-wave private LDS slice (exp'd once, coalesced),
// read back as one ds_read_b128 per step. Per-column power-of-2 rescale every 8 steps.
// fused1: blocks [0,4096) = phase1 chunk products; blocks [4096,5120) = gold score.
// combine: 1 wave/batch, 15 sequential MFMA products over chunk mats w/ exact scale algebra.

#define BB 1024
#define SS 1024
#define TT 16
#define CC 16
#define LL 64
#define P1B (BB * CC / 4)   // 4096 phase1 blocks

typedef float    f32x4 __attribute__((ext_vector_type(4)));
typedef int      i32x4 __attribute__((ext_vector_type(4)));
typedef short    s16x4 __attribute__((ext_vector_type(4)));
typedef uint32_t u32x2 __attribute__((ext_vector_type(2)));

// truncating f32->bf16 pack of (lo,hi) into one dword: single v_perm_b32
__device__ __forceinline__ uint32_t pkt(float lo, float hi) {
    return __builtin_amdgcn_perm(__float_as_uint(hi), __float_as_uint(lo), 0x07060302u);
}
__device__ __forceinline__ s16x4 mk_frag(uint32_t lo, uint32_t hi) {
    u32x2 t; t.x = lo; t.y = hi;
    return __builtin_bit_cast(s16x4, t);
}

__global__ __launch_bounds__(256) void fused1_kernel(
        const float* __restrict__ em,      // (B,S,T)
        const float* __restrict__ trans,   // (T,T)
        const int*   __restrict__ tags,    // (B,S) int32
        const float* __restrict__ startt,  // (T)
        const float* __restrict__ endt,    // (T)
        float* __restrict__ mats,          // (B*C,256)
        int*   __restrict__ scales,        // (B*C,16) per-column exponents
        float* __restrict__ gold)          // (B)
{
    __shared__ float xbuf[4][LL * TT];     // 4KB per wave, wave-private (no __syncthreads)
    __shared__ float red[256];
    if (blockIdx.x < P1B) {
        // ---------------- phase 1 ----------------
        const int wave = threadIdx.x >> 6;
        const int lane = threadIdx.x & 63;
        const int id   = blockIdx.x * 4 + wave;   // (b,c)
        const int b    = id >> 4;
        const int c    = id & 15;
        const int q    = lane >> 4;
        const int m    = lane & 15;

        // constant A = E (truncation-compensated): A[m][4q+j] = exp(trans[4q+j][m]) * comp
        const float comp = 1.00390625f;    // (1+2^-9)^2: A-const trunc + per-step B trunc
        const float a0 = __expf(trans[(4*q + 0) * TT + m]) * comp;
        const float a1 = __expf(trans[(4*q + 1) * TT + m]) * comp;
        const float a2 = __expf(trans[(4*q + 2) * TT + m]) * comp;
        const float a3 = __expf(trans[(4*q + 3) * TT + m]) * comp;
        const s16x4 afr = mk_frag(pkt(a0, a1), pkt(a2, a3));

        // scaled running product, D layout: sd[r] = P[4q+r][m]; identity start
        f32x4 sd;
        sd[0] = (4*q + 0 == m) ? 1.f : 0.f;
        sd[1] = (4*q + 1 == m) ? 1.f : 0.f;
        sd[2] = (4*q + 2 == m) ? 1.f : 0.f;
        sd[3] = (4*q + 3 == m) ? 1.f : 0.f;
        const f32x4 zero = {0.f, 0.f, 0.f, 0.f};
        int sc = 0;

        const float* ep = em + (size_t)b * SS * TT + (size_t)c * LL * TT + lane;
        float* xb = xbuf[wave];
        const bool skip0 = (c == 0);       // chunk 0 covers t=1..63 (t=0 is the init state)

#define RESCALE() {                                                         \
        float mx = fmaxf(fmaxf(sd[0], sd[1]), fmaxf(sd[2], sd[3]));         \
        mx = fmaxf(mx, __shfl_xor(mx, 16, 64));                             \
        mx = fmaxf(mx, __shfl_xor(mx, 32, 64));                             \
        const int e_ = (int)(__float_as_uint(mx) >> 23) - 127;              \
        const float sf_ = __uint_as_float((uint32_t)(127 - e_) << 23);      \
        sd[0] *= sf_; sd[1] *= sf_; sd[2] *= sf_; sd[3] *= sf_;             \
        sc += e_; }

        #pragma unroll
        for (int g = 0; g < 4; ++g) {
            // stage exp(em) for 16 steps: coalesced loads, lane-linear LDS writes (2-way, free)
            const float v0 = ep[g * 256 +   0];
            const float v1 = ep[g * 256 +  64];
            const float v2 = ep[g * 256 + 128];
            const float v3 = ep[g * 256 + 192];
            xb[g * 256 + lane +   0] = __expf(v0);
            xb[g * 256 + lane +  64] = __expf(v1);
            xb[g * 256 + lane + 128] = __expf(v2);
            xb[g * 256 + lane + 192] = __expf(v3);

            #pragma unroll
            for (int i = 0; i < 16; ++i) {
                if (!(skip0 && g == 0 && i == 0)) {   // wave-uniform scalar branch, i==0 only
                    const f32x4 xr = *(const f32x4*)(xb + g * 256 + i * TT + 4 * q);
                    const s16x4 bfr = mk_frag(pkt(sd[0], sd[1]), pkt(sd[2], sd[3]));
                    const f32x4 d = __builtin_amdgcn_mfma_f32_16x16x16bf16_1k(afr, bfr, zero, 0, 0, 0);
                    sd = d * xr;                       // fold diag(x_t) into next pack
                }
                if (i == 7 || i == 15) RESCALE();
            }
        }
#undef RESCALE

        float* mp = mats + (size_t)id * 256;
        mp[(4*q + 0) * TT + m] = sd[0];
        mp[(4*q + 1) * TT + m] = sd[1];
        mp[(4*q + 2) * TT + m] = sd[2];
        mp[(4*q + 3) * TT + m] = sd[3];
        if (q == 0) scales[id * 16 + m] = sc;     // per-column exponent
    } else {
        // ---------------- gold score ----------------
        const int b = blockIdx.x - P1B, tid = threadIdx.x;
        float local = 0.f;
        for (int t = tid; t < SS; t += 256) {
            const int tg = tags[b * SS + t];
            float v = em[(size_t)(b * SS + t) * TT + tg];
            if (t > 0) v += trans[tg * TT + tags[b * SS + t - 1]];  // trans[next, prev]
            else       v += startt[tg];
            if (t == SS - 1) v += endt[tg];                          // mask all-true
            local += v;
        }
        red[tid] = local; __syncthreads();
        for (int s = 128; s > 0; s >>= 1) { if (tid < s) red[tid] += red[tid + s]; __syncthreads(); }
        if (tid == 0) gold[b] = red[0];
    }
}

// ---------------- combine: MFMA chunk-product + epilogue + final reduce ----------------
__global__ __launch_bounds__(256) void combine_kernel(
        const float* __restrict__ em,
        const float* __restrict__ startt,
        const float* __restrict__ endt,
        const float* __restrict__ mats,
        const int*   __restrict__ scales,
        const float* __restrict__ gold,
        float* __restrict__ out)
{
    const int wave = threadIdx.x >> 6;
    const int lane = threadIdx.x & 63;
    const int b    = blockIdx.x * 4 + wave;   // one wave per batch
    const int q    = lane >> 4;
    const int m    = lane & 15;

    // init from chunk 0: d[r] = M_0[4q+r][m]; sigma = s_0[m]; gamma = 0
    const float* m0 = mats + (size_t)(b * CC) * 256;
    f32x4 d;
    d[0] = m0[(4*q + 0) * TT + m];
    d[1] = m0[(4*q + 1) * TT + m];
    d[2] = m0[(4*q + 2) * TT + m];
    d[3] = m0[(4*q + 3) * TT + m];
    int sig = scales[(b * CC) * 16 + m];
    int gam = 0;
    const f32x4 zero = {0.f, 0.f, 0.f, 0.f};

    #pragma unroll 4
    for (int c = 1; c < CC; ++c) {
        const int idc = b * CC + c;
        // A = M_c in A-layout: A[m][4q+j] -> contiguous f32x4
        const f32x4 a = *(const f32x4*)(mats + (size_t)idc * 256 + m * TT + 4 * q);
        // row scales s_c[4q+j], contiguous int4
        const i32x4 s = *(const i32x4*)(scales + idc * 16 + 4 * q);
        int sm = max(max(s.x, s.y), max(s.z, s.w));
        sm = max(sm, __shfl_xor(sm, 16, 64));
        sm = max(sm, __shfl_xor(sm, 32, 64));
        // B = diag(2^(s_c - sm)) * D_cur, bf16 (exponents <= 0, range-safe)
        const float r0 = ldexpf(d[0], s.x - sm);
        const float r1 = ldexpf(d[1], s.y - sm);
        const float r2 = ldexpf(d[2], s.z - sm);
        const float r3 = ldexpf(d[3], s.w - sm);
        const s16x4 bfr = mk_frag(pkt(r0, r1), pkt(r2, r3));
        const s16x4 afr = mk_frag(pkt(a.x, a.y), pkt(a.z, a.w));
        d = __builtin_amdgcn_mfma_f32_16x16x16bf16_1k(afr, bfr, zero, 0, 0, 0);
        gam += sm;
        // column rescale
        float mx = fmaxf(fmaxf(d[0], d[1]), fmaxf(d[2], d[3]));
        mx = fmaxf(mx, __shfl_xor(mx, 16, 64));
        mx = fmaxf(mx, __shfl_xor(mx, 32, 64));
        const int e = (int)(__float_as_uint(mx) >> 23) - 127;
        const float sf = __uint_as_float((uint32_t)(127 - e) << 23);
        d[0] *= sf; d[1] *= sf; d[2] *= sf; d[3] *= sf;
        sig += e;
    }

    // ---- epilogue: logZ = mx0 + ln2*(gam + sigmax) + log( end^T * V * w ) ----
    const float s0 = startt[m] + em[(size_t)b * SS * TT + m];
    float mx0 = s0;
    #pragma unroll
    for (int s = 1; s < 16; s <<= 1) mx0 = fmaxf(mx0, __shfl_xor(mx0, s, 64));
    const float u0n = __expf(s0 - mx0);

    int sigmax = sig;
    #pragma unroll
    for (int s = 1; s < 16; s <<= 1) sigmax = max(sigmax, __shfl_xor(sigmax, s, 64));
    const float w = ldexpf(u0n, sig - sigmax);     // per-column weight

    f32x4 v;
    v[0] = d[0] * w; v[1] = d[1] * w; v[2] = d[2] * w; v[3] = d[3] * w;
    #pragma unroll
    for (int s = 1; s < 16; s <<= 1) {
        v[0] += __shfl_xor(v[0], s, 64);
        v[1] += __shfl_xor(v[1], s, 64);
        v[2] += __shfl_xor(v[2], s, 64);
        v[3] += __shfl_xor(v[3], s, 64);
    }
    const f32x4 ee = *(const f32x4*)(endt + 4 * q);
    float z = __expf(ee.x) * v[0] + __expf(ee.y) * v[1]
            + __expf(ee.z) * v[2] + __expf(ee.w) * v[3];
    z += __shfl_xor(z, 16, 64);
    z += __shfl_xor(z, 32, 64);

    if (lane == 0) {
        const float logZ = mx0 + 0.69314718055994531f * (float)(gam + sigmax) + __logf(z);
        atomicAdd(out, (logZ - gold[b]) * (1.0f / BB));
    }
}

extern "C" void kernel_launch(void* const* d_in, const int* in_sizes, int n_in,
                              void* d_out, int out_size, void* d_ws, size_t ws_size,
                              hipStream_t stream) {
    const float* em     = (const float*)d_in[0];   // (B,S,T) fp32
    const int*   tags   = (const int*)  d_in[1];   // (B,S) int32
    // d_in[2] = mask, all ones -> ignored
    const float* trans  = (const float*)d_in[3];   // (T,T)
    const float* startt = (const float*)d_in[4];   // (T,)
    const float* endt   = (const float*)d_in[5];   // (T,)
    float* out = (float*)d_out;

    float* mats   = (float*)d_ws;                                          // 16 MB
    int*   scales = (int*)((char*)d_ws + (size_t)BB * CC * 256 * 4);       // 1 MB
    float* gold   = (float*)((char*)scales + (size_t)BB * CC * 16 * 4);    // 4 KB

    hipMemsetAsync(out, 0, sizeof(float), stream);
    fused1_kernel<<<P1B + BB, 256, 0, stream>>>(em, trans, tags, startt, endt, mats, scales, gold);
    combine_kernel<<<BB / 4, 256, 0, stream>>>(em, startt, endt, mats, scales, gold, out);
}